// Round 2
// baseline (402.822 us; speedup 1.0000x reference)
//
#include <hip/hip_runtime.h>
#include <math.h>

#define NROWS_DEF 131072
#define D 512
#define NB 64

// ws layout (float offsets)
#define OFF_LHG   0                    // 64*512 log hist probs
#define OFF_SPAR  (NB*D)               // 512 scale params
#define OFF_CPAR  (OFF_SPAR + D)       // 512 offset params
#define OFF_BMAX  (OFF_CPAR + D)       // 256 block maxes
#define OFF_GSUM  (OFF_BMAX + 256)     // 1 global sum

__device__ __forceinline__ int imin(int a, int b) { return a < b ? a : b; }
__device__ __forceinline__ int imax(int a, int b) { return a > b ? a : b; }

// ---------------- K1: log-hist + affine params + exact-uniformity check ----
__global__ __launch_bounds__(256) void k_prep(const float* __restrict__ freq,
                                              const float* __restrict__ edges,
                                              float* __restrict__ ws) {
    int d = blockIdx.x * 256 + threadIdx.x;
    if (d >= D) return;
    float sum = 0.f;
    for (int b = 0; b < NB; ++b) sum += freq[b * D + d];
    for (int b = 0; b < NB; ++b)
        ws[OFF_LHG + b * D + d] = logf(freq[b * D + d] / sum);

    float e0 = edges[d], e64 = edges[NB * D + d];
    float s = (float)NB / (e64 - e0);
    float c = -e0 * s;
    bool ok = (e64 > e0) && isfinite(s) && isfinite(c);
    float prev = e0;
    for (int b = 1; b <= NB; ++b) { float e = edges[b * D + d]; ok = ok && (e > prev); prev = e; }
    // verify every edge sits exactly on the affine grid (within << frac guard)
    for (int b = 0; b <= NB; ++b) {
        float t = fmaf(edges[b * D + d], s, c);
        ok = ok && (fabsf(t - (float)b) < 2e-5f);
    }
    ws[OFF_SPAR + d] = ok ? s : __int_as_float(0x7fc00000); // NaN => always exact path
    ws[OFF_CPAR + d] = c;
}

// exact np.searchsorted(edges[:,d], x, side='right') then clip(ins-1,0,63)
__device__ __forceinline__ int careful_bin(const float* __restrict__ edges, int d, float x) {
    int lo = 0, hi = NB + 1;
    while (lo < hi) {
        int mid = (lo + hi) >> 1;
        float e = edges[mid * D + d];
        if (e <= x) lo = mid + 1; else hi = mid;
    }
    return imin(NB - 1, imax(0, lo - 1));
}

__device__ __forceinline__ int bin_of(float x, float s, float c,
                                      const float* __restrict__ edges, int d) {
    float t  = fmaf(x, s, c);
    float fl = floorf(t);
    float fr = t - fl;
    int b = imin(NB - 1, imax(0, (int)fl));
    // fast path valid only if provably not on an edge boundary (NaN s => false)
    if (!((fr >= 1e-4f) && (fr <= 0.9999f)))
        b = careful_bin(edges, d, x);
    return b;
}

// ---------------- K2: main streaming pass, logits[r] = sum_d log p ---------
__global__ __launch_bounds__(1024, 4) void k_main(const float* __restrict__ in,
                                                  const float* __restrict__ edges,
                                                  const float* __restrict__ ws,
                                                  float* __restrict__ logits,
                                                  int nrows) {
    extern __shared__ float lh[]; // [D][65] transposed log-hist, stride 65 (bank = (lane+b)%32)
    for (int idx = threadIdx.x; idx < NB * D; idx += 1024) {
        int b = idx >> 9;        // bin
        int d = idx & (D - 1);   // feature
        lh[d * 65 + b] = ws[OFF_LHG + idx];
    }
    __syncthreads();

    const int lane = threadIdx.x & 63;
    const int wid  = threadIdx.x >> 6;

    float s[8], c[8];
    int   lb[8], dd[8];
    #pragma unroll
    for (int j = 0; j < 8; ++j) {
        int d = lane + 64 * j;
        dd[j] = d;
        s[j]  = ws[OFF_SPAR + d];
        c[j]  = ws[OFF_CPAR + d];
        lb[j] = d * 65;
    }

    const int r0 = blockIdx.x * 512;
    for (int r = r0 + wid * 2; r < r0 + 512; r += 32) {
        bool do0 = (r < nrows), do1 = (r + 1 < nrows);
        const float* rp0 = in + (size_t)r * D + lane;
        const float* rp1 = rp0 + D;
        float x0[8], x1[8];
        #pragma unroll
        for (int j = 0; j < 8; ++j) x0[j] = do0 ? rp0[64 * j] : 0.f;
        #pragma unroll
        for (int j = 0; j < 8; ++j) x1[j] = do1 ? rp1[64 * j] : 0.f;

        float a0 = 0.f, a1 = 0.f;
        #pragma unroll
        for (int j = 0; j < 8; ++j) {
            a0 += lh[lb[j] + bin_of(x0[j], s[j], c[j], edges, dd[j])];
            a1 += lh[lb[j] + bin_of(x1[j], s[j], c[j], edges, dd[j])];
        }
        #pragma unroll
        for (int off = 32; off > 0; off >>= 1) {
            a0 += __shfl_down(a0, off);
            a1 += __shfl_down(a1, off);
        }
        if (lane == 0) {
            if (do0) logits[r]     = a0;
            if (do1) logits[r + 1] = a1;
        }
    }
}

// ---------------- K3: per-block max ----------------------------------------
__global__ __launch_bounds__(256) void k_max(const float* __restrict__ logits,
                                             float* __restrict__ bmax, int n) {
    int tid = blockIdx.x * 256 + threadIdx.x;
    float m = -INFINITY;
    for (int i = tid; i < n; i += 256 * 256) m = fmaxf(m, logits[i]);
    #pragma unroll
    for (int off = 32; off > 0; off >>= 1) m = fmaxf(m, __shfl_down(m, off));
    __shared__ float sm[4];
    int lane = threadIdx.x & 63, wid = threadIdx.x >> 6;
    if (lane == 0) sm[wid] = m;
    __syncthreads();
    if (threadIdx.x == 0)
        bmax[blockIdx.x] = fmaxf(fmaxf(sm[0], sm[1]), fmaxf(sm[2], sm[3]));
}

// ---------------- K4: exp(l - gmax) in place + global sum ------------------
__global__ __launch_bounds__(256) void k_exp(float* __restrict__ io,
                                             const float* __restrict__ bmax,
                                             float* __restrict__ gsum, int n) {
    __shared__ float sm[4];
    int lane = threadIdx.x & 63, wid = threadIdx.x >> 6;
    float m = bmax[threadIdx.x];
    #pragma unroll
    for (int off = 32; off > 0; off >>= 1) m = fmaxf(m, __shfl_down(m, off));
    if (lane == 0) sm[wid] = m;
    __syncthreads();
    float gmax = fmaxf(fmaxf(sm[0], sm[1]), fmaxf(sm[2], sm[3]));
    __syncthreads();

    int tid = blockIdx.x * 256 + threadIdx.x;
    float lsum = 0.f;
    for (int i = tid; i < n; i += 256 * 256) {
        float e = expf(io[i] - gmax);
        io[i] = e;
        lsum += e;
    }
    #pragma unroll
    for (int off = 32; off > 0; off >>= 1) lsum += __shfl_down(lsum, off);
    if (lane == 0) sm[wid] = lsum;
    __syncthreads();
    if (threadIdx.x == 0) atomicAdd(gsum, sm[0] + sm[1] + sm[2] + sm[3]);
}

// ---------------- K5: scale ------------------------------------------------
__global__ __launch_bounds__(256) void k_scale(float* __restrict__ io,
                                               const float* __restrict__ gsum, int n) {
    float r = 1.0f / *gsum;
    int tid = blockIdx.x * 256 + threadIdx.x;
    for (int i = tid; i < n; i += 256 * 256) io[i] *= r;
}

extern "C" void kernel_launch(void* const* d_in, const int* in_sizes, int n_in,
                              void* d_out, int out_size, void* d_ws, size_t ws_size,
                              hipStream_t stream) {
    const float* inputs = (const float*)d_in[0];
    const float* freq   = (const float*)d_in[1];
    const float* edges  = (const float*)d_in[2];
    float* out = (float*)d_out;
    float* ws  = (float*)d_ws;
    const int nrows = in_sizes[0] / D;

    // zero the atomic sum accumulator (ws is poisoned each call)
    hipMemsetAsync((char*)d_ws + OFF_GSUM * sizeof(float), 0, sizeof(float), stream);

    k_prep<<<(D + 255) / 256, 256, 0, stream>>>(freq, edges, ws);

    const int lds_bytes = D * 65 * sizeof(float); // 133120
    hipFuncSetAttribute((const void*)k_main,
                        hipFuncAttributeMaxDynamicSharedMemorySize, lds_bytes);
    int nblk = (nrows + 511) / 512;
    k_main<<<nblk, 1024, lds_bytes, stream>>>(inputs, edges, ws, out, nrows);

    k_max<<<256, 256, 0, stream>>>(out, ws + OFF_BMAX, nrows);
    k_exp<<<256, 256, 0, stream>>>(out, ws + OFF_BMAX, ws + OFF_GSUM, nrows);
    k_scale<<<256, 256, 0, stream>>>(out, ws + OFF_GSUM, nrows);
}

// Round 3
// 388.084 us; speedup vs baseline: 1.0380x; 1.0380x over previous
//
#include <hip/hip_runtime.h>
#include <math.h>

#define D 512
#define NB 64

// ws layout (float offsets)
#define OFF_LHG   0                      // 64*512 log hist probs
#define OFF_SPAR  (NB*D)                 // 512 scale params
#define OFF_CPAR  (OFF_SPAR + D)         // 512 offset params
#define OFF_PART  (OFF_CPAR + D)         // per-wave (m, s) pairs
#define MAXPART   16384
#define OFF_RES   (OFF_PART + 2*MAXPART) // M, invS

static __device__ __forceinline__ int imin(int a, int b) { return a < b ? a : b; }
static __device__ __forceinline__ int imax(int a, int b) { return a > b ? a : b; }

// ---------------- K1: log-hist + affine params + exact-grid check ----------
__global__ __launch_bounds__(512) void k_prep(const float* __restrict__ freq,
                                              const float* __restrict__ edges,
                                              float* __restrict__ ws) {
    int d = threadIdx.x; // 512 threads, D features
    float sum = 0.f;
    for (int b = 0; b < NB; ++b) sum += freq[b * D + d];
    float inv = 1.0f / sum;
    for (int b = 0; b < NB; ++b)
        ws[OFF_LHG + b * D + d] = logf(freq[b * D + d] * inv);

    float e0 = edges[d], e64 = edges[NB * D + d];
    float s = (float)NB / (e64 - e0);
    float c = -e0 * s;
    bool ok = (e64 > e0) && isfinite(s) && isfinite(c);
    float prev = e0;
    for (int b = 1; b <= NB; ++b) { float e = edges[b * D + d]; ok = ok && (e > prev); prev = e; }
    // every edge must sit on the affine grid (margin << frac guard 4e-5)
    for (int b = 0; b <= NB; ++b) {
        float t = fmaf(edges[b * D + d], s, c);
        ok = ok && (fabsf(t - (float)b) < 2e-5f);
    }
    ws[OFF_SPAR + d] = ok ? s : __int_as_float(0x7fc00000); // NaN => exact path
    ws[OFF_CPAR + d] = c;
}

// exact np.searchsorted(edges[:,d], x, 'right') then clip (general fallback)
static __device__ __forceinline__ int careful_bin(const float* __restrict__ edges,
                                                  int d, float x) {
    int lo = 0, hi = NB + 1;
    while (lo < hi) {
        int mid = (lo + hi) >> 1;
        float e = edges[mid * D + d];
        if (e <= x) lo = mid + 1; else hi = mid;
    }
    return imin(NB - 1, imax(0, lo - 1));
}

static __device__ __forceinline__ int bin_of(float x, float s, float c,
                                             const float* __restrict__ edges, int d) {
    float t  = fmaf(x, s, c);
    float fl = floorf(t);
    float fr = t - fl;
    int b = imin(NB - 1, imax(0, (int)fl));
    // fast path valid only if provably not on an edge boundary (NaN s => false)
    if (__builtin_expect(!(fr >= 4e-5f && fr <= 0.99996f), 0)) {
        if (!__builtin_isnan(s)) {
            // t within eps of integer kk: bin decided by one exact edge compare
            int kk = imin(NB, imax(0, (int)rintf(t)));
            float e = edges[kk * D + d];
            b = imin(NB - 1, imax(0, (x >= e) ? kk : kk - 1));
        } else {
            b = careful_bin(edges, d, x);
        }
    }
    return b;
}

// ---------------- K2: main streaming pass ----------------------------------
// logits[r] = sum_d log p; also per-wave online (max, sumexp) partials.
__global__ __launch_bounds__(1024) void k_main(const float* __restrict__ in,
                                               const float* __restrict__ edges,
                                               const float* __restrict__ ws,
                                               float* __restrict__ logits,
                                               float* __restrict__ part,
                                               int nrows) {
    extern __shared__ float lh[]; // [D][65]: bank = (d+b)%32, lanes d-consecutive
    for (int idx = threadIdx.x; idx < NB * D; idx += 1024) {
        int b = idx >> 9;       // bin
        int d = idx & (D - 1);  // feature
        lh[d * 65 + b] = ws[OFF_LHG + idx];
    }
    __syncthreads();

    const int lane = threadIdx.x & 63;
    const int wid  = threadIdx.x >> 6;

    float s[8], c[8]; int lb[8];
    #pragma unroll
    for (int j = 0; j < 8; ++j) {
        int d = lane + 64 * j;
        s[j]  = ws[OFF_SPAR + d];
        c[j]  = ws[OFF_CPAR + d];
        lb[j] = d * 65;
    }

    float m = -INFINITY, ssum = 0.f;
    const int r0 = blockIdx.x * 512;
    const bool full = (r0 + 512 <= nrows);

    for (int k = 0; k < 8; ++k) {
        const int r = r0 + wid * 4 + k * 64;
        if (full || r + 4 <= nrows) {
            const float* rp = in + (size_t)r * D + lane;
            float x[4][8];
            #pragma unroll
            for (int i = 0; i < 4; ++i)
                #pragma unroll
                for (int j = 0; j < 8; ++j)
                    x[i][j] = rp[i * D + 64 * j];
            float a[4] = {0.f, 0.f, 0.f, 0.f};
            #pragma unroll
            for (int i = 0; i < 4; ++i)
                #pragma unroll
                for (int j = 0; j < 8; ++j)
                    a[i] += lh[lb[j] + bin_of(x[i][j], s[j], c[j], edges, lane + 64 * j)];
            #pragma unroll
            for (int i = 0; i < 4; ++i)
                #pragma unroll
                for (int off = 32; off; off >>= 1)
                    a[i] += __shfl_xor(a[i], off);
            if (lane == 0) {
                logits[r]     = a[0];
                logits[r + 1] = a[1];
                logits[r + 2] = a[2];
                logits[r + 3] = a[3];
            }
            #pragma unroll
            for (int i = 0; i < 4; ++i) {
                float mo = m;
                m = fmaxf(m, a[i]);
                ssum = ssum * __expf(mo - m) + __expf(a[i] - m);
            }
        } else {
            // tail block: row-at-a-time, guarded (not taken when nrows % 512 == 0)
            for (int i = 0; i < 4; ++i) {
                int rr = r + i;
                if (rr >= nrows) break;
                const float* rp = in + (size_t)rr * D + lane;
                float a = 0.f;
                #pragma unroll
                for (int j = 0; j < 8; ++j)
                    a += lh[lb[j] + bin_of(rp[64 * j], s[j], c[j], edges, lane + 64 * j)];
                #pragma unroll
                for (int off = 32; off; off >>= 1) a += __shfl_xor(a, off);
                if (lane == 0) logits[rr] = a;
                float mo = m;
                m = fmaxf(m, a);
                ssum = ssum * __expf(mo - m) + __expf(a - m);
            }
        }
    }
    if (lane == 0) {
        int w = blockIdx.x * 16 + wid;
        part[2 * w]     = m;
        part[2 * w + 1] = ssum;
    }
}

// ---------------- K3: combine per-wave partials -> (M, 1/S) ----------------
__global__ __launch_bounds__(1024) void k_combine(const float* __restrict__ part,
                                                  float* __restrict__ res, int npart) {
    float m = -INFINITY, s = 0.f;
    for (int i = threadIdx.x; i < npart; i += 1024) {
        float pm = part[2 * i], ps = part[2 * i + 1];
        float mn = fmaxf(m, pm);
        if (mn > -INFINITY) s = s * __expf(m - mn) + ps * __expf(pm - mn);
        m = mn;
    }
    #pragma unroll
    for (int off = 32; off; off >>= 1) {
        float pm = __shfl_xor(m, off), ps = __shfl_xor(s, off);
        float mn = fmaxf(m, pm);
        if (mn > -INFINITY) s = s * __expf(m - mn) + ps * __expf(pm - mn);
        else s = 0.f;
        m = mn;
    }
    __shared__ float sm[16][2];
    int lane = threadIdx.x & 63, wid = threadIdx.x >> 6;
    if (lane == 0) { sm[wid][0] = m; sm[wid][1] = s; }
    __syncthreads();
    if (wid == 0) {
        m = (lane < 16) ? sm[lane][0] : -INFINITY;
        s = (lane < 16) ? sm[lane][1] : 0.f;
        #pragma unroll
        for (int off = 8; off; off >>= 1) {
            float pm = __shfl_xor(m, off), ps = __shfl_xor(s, off);
            float mn = fmaxf(m, pm);
            if (mn > -INFINITY) s = s * __expf(m - mn) + ps * __expf(pm - mn);
            else s = 0.f;
            m = mn;
        }
        if (lane == 0) { res[0] = m; res[1] = 1.0f / s; }
    }
}

// ---------------- K4: out = exp(l - M) * invS, in place, float2 ------------
__global__ __launch_bounds__(256) void k_final(float* __restrict__ io,
                                               const float* __restrict__ res, int n) {
    float M = res[0], invS = res[1];
    float2* io2 = (float2*)io;
    int n2 = n >> 1;
    for (int idx = blockIdx.x * 256 + threadIdx.x; idx < n2; idx += gridDim.x * 256) {
        float2 v = io2[idx];
        v.x = __expf(v.x - M) * invS;
        v.y = __expf(v.y - M) * invS;
        io2[idx] = v;
    }
    if (blockIdx.x == 0 && threadIdx.x == 0 && (n & 1))
        io[n - 1] = __expf(io[n - 1] - M) * invS;
}

extern "C" void kernel_launch(void* const* d_in, const int* in_sizes, int n_in,
                              void* d_out, int out_size, void* d_ws, size_t ws_size,
                              hipStream_t stream) {
    const float* inputs = (const float*)d_in[0];
    const float* freq   = (const float*)d_in[1];
    const float* edges  = (const float*)d_in[2];
    float* out = (float*)d_out;
    float* ws  = (float*)d_ws;
    const int nrows = in_sizes[0] / D;
    const int nblk  = (nrows + 511) / 512;
    const int npart = nblk * 16;

    k_prep<<<1, 512, 0, stream>>>(freq, edges, ws);

    const int lds_bytes = D * 65 * sizeof(float); // 133120
    hipFuncSetAttribute((const void*)k_main,
                        hipFuncAttributeMaxDynamicSharedMemorySize, lds_bytes);
    k_main<<<nblk, 1024, lds_bytes, stream>>>(inputs, edges, ws, out,
                                              ws + OFF_PART, nrows);

    k_combine<<<1, 1024, 0, stream>>>(ws + OFF_PART, ws + OFF_RES, npart);
    k_final<<<256, 256, 0, stream>>>(out, ws + OFF_RES, nrows);
}